// Round 1
// baseline (176.329 us; speedup 1.0000x reference)
//
#include <hip/hip_runtime.h>

// GraphAttentionLayer, B=8, N=1024, F_IN=64, HEADS=8, D=64.
// exp(leaky_relu(s_i + t_j)) factorizes across the LeakyReLU branch:
//   [s_i+t_j>0] e^{s_i} e^{t_j} + [s_i+t_j<=0] e^{0.01 s_i} e^{0.01 t_j}
// so softmax denominators (over i) and the weighted sum over j reduce to
// prefix sums over sorted s / sorted t.  O(N^2 D) -> O(N log N + N D).
//
// R3 changes (LDS-broadcast elimination):
//  - k_wh: h values are wave-uniform per (r,k) -> read directly from global
//    with uniform float4 indices (compiler emits s_load_dwordx4, SMEM pipe)
//    instead of 1024 scalar ds_read_b32 broadcasts per wave.
//  - k_out split into k_hp (computes hp to global, full lane parallelism)
//    + k_gemm (hp @ outW + b with hp via uniform scalar loads).
//    hp[r][k] is wave-uniform in the GEMM -> SMEM, freeing the LDS pipe.

#define B_  8
#define N_  1024
#define H_  8
#define D_  64
#define BH_ 64
#define CH_ 32          // chunks per (b,h)
#define CL_ 32          // ranks per chunk

// ---------------- Kernel A: Wh = h@W (row-blocked), s/t = Wh . a ----------
__global__ __launch_bounds__(256) void k_wh(
    const float* __restrict__ h, const float* __restrict__ W,
    const float* __restrict__ a,
    float* __restrict__ Wh, float* __restrict__ sArr, float* __restrict__ tArr) {
  __shared__ float whL[16 * 512];
  __shared__ float aL[128];
  const int tid = threadIdx.x;
  const int row0 = blockIdx.x * 16;
  const int b = row0 >> 10;
  if (tid < 128) aL[tid] = a[tid];

  float acc0[16], acc1[16];
#pragma unroll
  for (int r = 0; r < 16; ++r) { acc0[r] = 0.f; acc1[r] = 0.f; }
  for (int k0 = 0; k0 < 64; k0 += 4) {
    float w0[4], w1[4];
#pragma unroll
    for (int u = 0; u < 4; ++u) {
      w0[u] = W[(k0 + u) * 512 + tid];
      w1[u] = W[(k0 + u) * 512 + tid + 256];
    }
#pragma unroll
    for (int r = 0; r < 16; ++r) {
      // uniform address (blockIdx + loop vars only) -> s_load_dwordx4
      const float4 hv = *reinterpret_cast<const float4*>(&h[(row0 + r) * 64 + k0]);
      acc0[r] += hv.x * w0[0] + hv.y * w0[1] + hv.z * w0[2] + hv.w * w0[3];
      acc1[r] += hv.x * w1[0] + hv.y * w1[1] + hv.z * w1[2] + hv.w * w1[3];
    }
  }
  const int hh0 = tid >> 6, d0 = tid & 63;
  const int hh1 = (tid + 256) >> 6;
#pragma unroll
  for (int r = 0; r < 16; ++r) {
    const int n = (row0 + r) & (N_ - 1);
    whL[r * 512 + tid] = acc0[r];
    whL[r * 512 + tid + 256] = acc1[r];
    Wh[((b * H_ + hh0) * N_ + n) * D_ + d0] = acc0[r];
    Wh[((b * H_ + hh1) * N_ + n) * D_ + d0] = acc1[r];
  }
  __syncthreads();
  if (tid < 128) {
    const int r = tid >> 3, hh = tid & 7;
    const int n = (row0 + r) & (N_ - 1);
    float accS = 0.f, accT = 0.f;
    for (int jj = 0; jj < 64; ++jj) {
      const int d = (jj + tid) & 63;
      const float wv = whL[r * 512 + hh * 64 + d];
      accS += wv * aL[d];
      accT += wv * aL[64 + d];
    }
    sArr[(b * H_ + hh) * N_ + n] = accS;
    tArr[(b * H_ + hh) * N_ + n] = accT;
  }
}

// ---- Kernel B: per (b,h): dual shfl-bitonic sort, shfl scans, Z/u/v,
//      query ranks, chunk sums + exclusive chunk offsets ----
__global__ __launch_bounds__(1024) void k_sort(
    const float* __restrict__ sArr, const float* __restrict__ tArr,
    const float* __restrict__ Wh,
    int* __restrict__ tsi, float* __restrict__ uArr, float* __restrict__ vArr,
    int* __restrict__ qrk,
    float* __restrict__ cOff1, float* __restrict__ cOff2) {
  __shared__ float sL[1024];
  __shared__ float tvL[1024];
  __shared__ int   tiL[1024];
  __shared__ float cum1L[1024], cum001L[1024];
  __shared__ float uL[1024], vL[1024];
  __shared__ float cs1[CH_ * 64], cs2[CH_ * 64];
  __shared__ float ws1[16], ws2[16];
  const int tid = threadIdx.x;
  const int lane = tid & 63;
  const int wv_ = tid >> 6;
  const int bh = blockIdx.x;

  const float orig_s = sArr[bh * N_ + tid];
  float sv_r = orig_s;
  float tv_r = tArr[bh * N_ + tid];
  int   ti_r = tid;

  // bitonic sort ascending; strides<64 via shfl (no barrier), >=64 via LDS
  for (int size = 2; size <= 1024; size <<= 1) {
    for (int stride = size >> 1; stride > 0; stride >>= 1) {
      const bool up = ((tid & size) == 0);
      const bool lower = ((tid & stride) == 0);
      float psv, ptv; int pti;
      if (stride >= 64) {
        sL[tid] = sv_r; tvL[tid] = tv_r; tiL[tid] = ti_r;
        __syncthreads();
        const int p = tid ^ stride;
        psv = sL[p]; ptv = tvL[p]; pti = tiL[p];
        __syncthreads();
      } else {
        psv = __shfl_xor(sv_r, stride);
        ptv = __shfl_xor(tv_r, stride);
        pti = __shfl_xor(ti_r, stride);
      }
      const bool sameDir = (up == lower);
      // s: value-only (ties harmless)
      const bool pLessS = (psv < sv_r);
      if (pLessS == sameDir) sv_r = psv;
      // t: lexicographic (value, idx) for a strict total order
      const bool pLessT = (ptv < tv_r) || (ptv == tv_r && pti < ti_r);
      if (pLessT == sameDir) { tv_r = ptv; ti_r = pti; }
    }
  }
  sL[tid] = sv_r; tvL[tid] = tv_r; tiL[tid] = ti_r;

  // inclusive scans of exp(s), exp(0.01 s) in sorted order: wave scan + fixup
  float c1 = __expf(sv_r) , c001 = __expf(0.01f * sv_r);
  {
    float a1 = c1, a2 = c001;
#pragma unroll
    for (int off = 1; off < 64; off <<= 1) {
      const float x1 = __shfl_up(a1, off);
      const float x2 = __shfl_up(a2, off);
      if (lane >= off) { a1 += x1; a2 += x2; }
    }
    if (lane == 63) { ws1[wv_] = a1; ws2[wv_] = a2; }
    __syncthreads();
    float o1 = 0.f, o2 = 0.f;
    for (int ww = 0; ww < 16; ++ww) {
      if (ww < wv_) { o1 += ws1[ww]; o2 += ws2[ww]; }
    }
    c1 = a1 + o1; c001 = a2 + o2;
  }
  cum1L[tid] = c1; cum001L[tid] = c001;
  __syncthreads();
  const float totalHi = cum1L[1023];

  // per sorted-t rank: Z, u = e^t/Z, v = e^{0.01t}/Z
  {
    const float tj = tv_r;
    const float th = -tj;
    int lo = 0, hi = 1024;   // count of sorted-s <= th
    while (lo < hi) { const int mid = (lo + hi) >> 1; if (sL[mid] <= th) lo = mid + 1; else hi = mid; }
    const float S_lo = (lo > 0) ? cum001L[lo - 1] : 0.f;
    const float S_hi = totalHi - ((lo > 0) ? cum1L[lo - 1] : 0.f);
    const float et = __expf(tj), et001 = __expf(0.01f * tj);
    const float Z = et * S_hi + et001 * S_lo;
    const float u = et / Z, v = et001 / Z;
    uL[tid] = u; vL[tid] = v;
    uArr[bh * N_ + tid] = u; vArr[bh * N_ + tid] = v;
    tsi[bh * N_ + tid] = ti_r;
  }

  // query rank for row i=tid: count of t_j <= -s_i (value-only, ties ok)
  {
    const float th = -orig_s;
    int lo = 0, hi = 1024;
    while (lo < hi) { const int mid = (lo + hi) >> 1; if (tvL[mid] <= th) lo = mid + 1; else hi = mid; }
    qrk[bh * N_ + tid] = lo;
  }
  __syncthreads();

  // chunk sums (CH_ chunks of CL_ ranks) of u*Wh, v*Wh + exclusive offsets
  const int c = tid >> 6, d = tid & 63;
#pragma unroll
  for (int half = 0; half < 2; ++half) {
    const int cc = c + half * 16;
    float s1 = 0.f, s2 = 0.f;
    for (int k2 = 0; k2 < CL_; ++k2) {
      const int k = cc * CL_ + k2;
      const int j = tiL[k];
      const float w = Wh[(bh * N_ + j) * D_ + d];
      s1 += uL[k] * w;
      s2 += vL[k] * w;
    }
    cs1[cc * 64 + d] = s1; cs2[cc * 64 + d] = s2;
  }
  __syncthreads();
#pragma unroll
  for (int half = 0; half < 2; ++half) {
    const int cc = c + half * 16;
    float o1 = 0.f, o2 = 0.f;
    for (int m = 0; m < cc; ++m) { o1 += cs1[m * 64 + d]; o2 += cs2[m * 64 + d]; }
    cOff1[(bh * CH_ + cc) * 64 + d] = o1;
    cOff2[(bh * CH_ + cc) * 64 + d] = o2;
  }
}

// ---- Kernel C: inclusive per-rank prefix vectors INC1/INC2 (chunk len 32) --
__global__ __launch_bounds__(64) void k_inc(
    const float* __restrict__ Wh, const int* __restrict__ tsi,
    const float* __restrict__ uArr, const float* __restrict__ vArr,
    const float* __restrict__ cOff1, const float* __restrict__ cOff2,
    float* __restrict__ INC1, float* __restrict__ INC2) {
  const int blk = blockIdx.x;            // bh*CH_ + chunk
  const int bh = blk >> 5, c = blk & (CH_ - 1);
  const int d = threadIdx.x;
  float r1 = cOff1[blk * 64 + d];
  float r2 = cOff2[blk * 64 + d];
  const int base = bh * N_;
#pragma unroll 8
  for (int k2 = 0; k2 < CL_; ++k2) {
    const int k = c * CL_ + k2;
    const int j = tsi[base + k];
    const float u = uArr[base + k], v = vArr[base + k];
    const float w = Wh[(base + j) * D_ + d];
    r1 += u * w;
    r2 += v * w;
    INC1[(base + k) * D_ + d] = r1;
    INC2[(base + k) * D_ + d] = r2;
  }
}

// ---- Kernel D: hp[row][k] = es*(T1-I1[rk-1]) + es001*I2[rk-1]  -> global --
__global__ __launch_bounds__(512) void k_hp(
    const float* __restrict__ sArr, const int* __restrict__ qrk,
    const float* __restrict__ INC1, const float* __restrict__ INC2,
    float* __restrict__ hp) {
  __shared__ int   rkI[16 * 8];
  __shared__ float esL[16 * 8], es001L[16 * 8];
  const int tid = threadIdx.x;
  const int row0 = blockIdx.x * 16;
  const int b = row0 >> 10;

  if (tid < 128) {
    const int r = tid >> 3, hh = tid & 7;
    const int bh = b * H_ + hh;
    const int n = (row0 + r) & (N_ - 1);
    const float si = sArr[bh * N_ + n];
    rkI[tid] = qrk[bh * N_ + n];
    esL[tid] = __expf(si);
    es001L[tid] = __expf(0.01f * si);
  }
  __syncthreads();

  const int hh = tid >> 6, d = tid & 63;
  const int bh = b * H_ + hh;
  const float T1 = INC1[(bh * N_ + (N_ - 1)) * D_ + d];
#pragma unroll
  for (int r = 0; r < 16; ++r) {
    const int rk = rkI[r * 8 + hh];
    float i1 = 0.f, i2 = 0.f;
    if (rk > 0) {
      i1 = INC1[(bh * N_ + rk - 1) * D_ + d];
      i2 = INC2[(bh * N_ + rk - 1) * D_ + d];
    }
    hp[(row0 + r) * 512 + hh * 64 + d] =
        esL[r * 8 + hh] * (T1 - i1) + es001L[r * 8 + hh] * i2;
  }
}

// ---- Kernel E: out = hp @ outW + b, hp via wave-uniform scalar loads ------
__global__ __launch_bounds__(512) void k_gemm(
    const float* __restrict__ hp, const float* __restrict__ outW,
    const float* __restrict__ outb, float* __restrict__ out) {
  __shared__ float part[8 * 8 * 64];
  const int tid = threadIdx.x;
  const int row0 = blockIdx.x * 16;
  const int cc = tid & 63;
  // readfirstlane: make the k-partition formally uniform so divergence
  // analysis allows SMEM (s_load) selection for the hp reads below.
  const int p = __builtin_amdgcn_readfirstlane(tid >> 6);

  float acc[16];
#pragma unroll
  for (int r = 0; r < 16; ++r) acc[r] = 0.f;

  for (int kc = 0; kc < 64; kc += 4) {
    const int k = p * 64 + kc;
    float wv[4];
#pragma unroll
    for (int u = 0; u < 4; ++u) wv[u] = outW[(k + u) * 64 + cc];
#pragma unroll
    for (int r = 0; r < 16; ++r) {
      // uniform address -> s_load_dwordx4 (SMEM pipe, no LDS broadcast)
      const float4 hv = *reinterpret_cast<const float4*>(&hp[(row0 + r) * 512 + k]);
      acc[r] += hv.x * wv[0] + hv.y * wv[1] + hv.z * wv[2] + hv.w * wv[3];
    }
  }

  for (int half = 0; half < 2; ++half) {
#pragma unroll
    for (int r = 0; r < 8; ++r) part[(p * 8 + r) * 64 + cc] = acc[half * 8 + r];
    __syncthreads();
    {
      const int r2 = tid >> 6, c2 = tid & 63;
      float ssum = 0.f;
#pragma unroll
      for (int p2 = 0; p2 < 8; ++p2) ssum += part[(p2 * 8 + r2) * 64 + c2];
      out[(row0 + half * 8 + r2) * 64 + c2] = outb[c2] + ssum;
    }
    __syncthreads();
  }
}

extern "C" void kernel_launch(void* const* d_in, const int* in_sizes, int n_in,
                              void* d_out, int out_size, void* d_ws, size_t ws_size,
                              hipStream_t stream) {
  const float* h    = (const float*)d_in[0];
  // d_in[1] = adj: all-ones, unused by the module
  const float* W    = (const float*)d_in[2];
  const float* a    = (const float*)d_in[3];
  const float* outW = (const float*)d_in[4];
  const float* outb = (const float*)d_in[5];
  float* out = (float*)d_out;

  float* ws   = (float*)d_ws;
  float* Wh   = ws;                                   // BH*N*D
  float* sArr = Wh + (size_t)BH_ * N_ * D_;           // BH*N
  float* tArr = sArr + BH_ * N_;
  int*   tsi  = (int*)(tArr + BH_ * N_);
  float* uArr = (float*)(tsi + BH_ * N_);
  float* vArr = uArr + BH_ * N_;
  int*   qrk  = (int*)(vArr + BH_ * N_);
  float* cOff1 = (float*)(qrk + BH_ * N_);            // BH*CH_*64
  float* cOff2 = cOff1 + BH_ * CH_ * 64;
  float* INC1 = cOff2 + BH_ * CH_ * 64;               // BH*N*D
  float* INC2 = INC1 + (size_t)BH_ * N_ * D_;
  float* hp   = INC2 + (size_t)BH_ * N_ * D_;         // (B*N) * 512

  hipLaunchKernelGGL(k_wh,   dim3((B_ * N_) / 16), dim3(256), 0, stream,
                     h, W, a, Wh, sArr, tArr);
  hipLaunchKernelGGL(k_sort, dim3(BH_), dim3(1024), 0, stream,
                     sArr, tArr, Wh, tsi, uArr, vArr, qrk, cOff1, cOff2);
  hipLaunchKernelGGL(k_inc,  dim3(BH_ * CH_), dim3(64), 0, stream,
                     Wh, tsi, uArr, vArr, cOff1, cOff2, INC1, INC2);
  hipLaunchKernelGGL(k_hp,   dim3((B_ * N_) / 16), dim3(512), 0, stream,
                     sArr, qrk, INC1, INC2, hp);
  hipLaunchKernelGGL(k_gemm, dim3((B_ * N_) / 16), dim3(512), 0, stream,
                     hp, outW, outb, out);
}

// Round 2
// 154.864 us; speedup vs baseline: 1.1386x; 1.1386x over previous
//
#include <hip/hip_runtime.h>

// GraphAttentionLayer, B=8, N=1024, F_IN=64, HEADS=8, D=64.
// exp(leaky_relu(s_i + t_j)) factorizes across the LeakyReLU branch:
//   [s_i+t_j>0] e^{s_i} e^{t_j} + [s_i+t_j<=0] e^{0.01 s_i} e^{0.01 t_j}
// so softmax denominators (over i) and the weighted sum over j reduce to
// prefix sums over sorted s / sorted t.  O(N^2 D) -> O(N log N + N D).
//
// R4 changes (back to R2 structure; LDS broadcasts -> v_readlane):
//  - k_wh: h rows live in VGPRs (lane l holds h[row][l]); the wave-uniform
//    multiplier h[row][k] comes from v_readlane_b32 (SGPR), not ds_read_b32
//    broadcasts.  Main-loop LDS traffic: 1024 instrs/wave -> 0.
//  - k_out: wave p's GEMM k-slice (k=p*64+kc) is exactly the hp slice that
//    thread (hh=p,d=lane) computes in phase 1 -> keep hpv[16] in registers,
//    broadcast via readlane(hpv[r],kc).  hpL (32KB LDS) eliminated entirely.
//  - No hp global round-trip, no extra kernel (reverts R3's split).

#define B_  8
#define N_  1024
#define H_  8
#define D_  64
#define BH_ 64
#define CH_ 32          // chunks per (b,h)
#define CL_ 32          // ranks per chunk

__device__ __forceinline__ float bcast_lane(float v, int l) {
  return __int_as_float(__builtin_amdgcn_readlane(__float_as_int(v), l));
}

// ---------------- Kernel A: Wh = h@W (row-blocked), s/t = Wh . a ----------
__global__ __launch_bounds__(256) void k_wh(
    const float* __restrict__ h, const float* __restrict__ W,
    const float* __restrict__ a,
    float* __restrict__ Wh, float* __restrict__ sArr, float* __restrict__ tArr) {
  __shared__ float whL[16 * 512];
  __shared__ float aL[128];
  const int tid = threadIdx.x;
  const int lane = tid & 63;
  const int row0 = blockIdx.x * 16;
  const int b = row0 >> 10;
  if (tid < 128) aL[tid] = a[tid];

  // lane l of every wave holds h[row0+r][l]
  float hreg[16];
#pragma unroll
  for (int r = 0; r < 16; ++r) hreg[r] = h[(row0 + r) * 64 + lane];

  float acc0[16], acc1[16];
#pragma unroll
  for (int r = 0; r < 16; ++r) { acc0[r] = 0.f; acc1[r] = 0.f; }
#pragma unroll 4
  for (int k = 0; k < 64; ++k) {
    const float w0 = W[k * 512 + tid];
    const float w1 = W[k * 512 + tid + 256];
#pragma unroll
    for (int r = 0; r < 16; ++r) {
      const float hv = bcast_lane(hreg[r], k);   // SGPR broadcast, no LDS
      acc0[r] += hv * w0;
      acc1[r] += hv * w1;
    }
  }
  const int hh0 = tid >> 6, d0 = tid & 63;
  const int hh1 = (tid + 256) >> 6;
#pragma unroll
  for (int r = 0; r < 16; ++r) {
    const int n = (row0 + r) & (N_ - 1);
    whL[r * 512 + tid] = acc0[r];
    whL[r * 512 + tid + 256] = acc1[r];
    Wh[((b * H_ + hh0) * N_ + n) * D_ + d0] = acc0[r];
    Wh[((b * H_ + hh1) * N_ + n) * D_ + d0] = acc1[r];
  }
  __syncthreads();
  if (tid < 128) {
    const int r = tid >> 3, hh = tid & 7;
    const int n = (row0 + r) & (N_ - 1);
    float accS = 0.f, accT = 0.f;
    for (int jj = 0; jj < 64; ++jj) {
      const int d = (jj + tid) & 63;
      const float wv = whL[r * 512 + hh * 64 + d];
      accS += wv * aL[d];
      accT += wv * aL[64 + d];
    }
    sArr[(b * H_ + hh) * N_ + n] = accS;
    tArr[(b * H_ + hh) * N_ + n] = accT;
  }
}

// ---- Kernel B: per (b,h): dual shfl-bitonic sort, shfl scans, Z/u/v,
//      query ranks, chunk sums + exclusive chunk offsets ----
__global__ __launch_bounds__(1024) void k_sort(
    const float* __restrict__ sArr, const float* __restrict__ tArr,
    const float* __restrict__ Wh,
    int* __restrict__ tsi, float* __restrict__ uArr, float* __restrict__ vArr,
    int* __restrict__ qrk,
    float* __restrict__ cOff1, float* __restrict__ cOff2) {
  __shared__ float sL[1024];
  __shared__ float tvL[1024];
  __shared__ int   tiL[1024];
  __shared__ float cum1L[1024], cum001L[1024];
  __shared__ float uL[1024], vL[1024];
  __shared__ float cs1[CH_ * 64], cs2[CH_ * 64];
  __shared__ float ws1[16], ws2[16];
  const int tid = threadIdx.x;
  const int lane = tid & 63;
  const int wv_ = tid >> 6;
  const int bh = blockIdx.x;

  const float orig_s = sArr[bh * N_ + tid];
  float sv_r = orig_s;
  float tv_r = tArr[bh * N_ + tid];
  int   ti_r = tid;

  // bitonic sort ascending; strides<64 via shfl (no barrier), >=64 via LDS
  for (int size = 2; size <= 1024; size <<= 1) {
    for (int stride = size >> 1; stride > 0; stride >>= 1) {
      const bool up = ((tid & size) == 0);
      const bool lower = ((tid & stride) == 0);
      float psv, ptv; int pti;
      if (stride >= 64) {
        sL[tid] = sv_r; tvL[tid] = tv_r; tiL[tid] = ti_r;
        __syncthreads();
        const int p = tid ^ stride;
        psv = sL[p]; ptv = tvL[p]; pti = tiL[p];
        __syncthreads();
      } else {
        psv = __shfl_xor(sv_r, stride);
        ptv = __shfl_xor(tv_r, stride);
        pti = __shfl_xor(ti_r, stride);
      }
      const bool sameDir = (up == lower);
      // s: value-only (ties harmless)
      const bool pLessS = (psv < sv_r);
      if (pLessS == sameDir) sv_r = psv;
      // t: lexicographic (value, idx) for a strict total order
      const bool pLessT = (ptv < tv_r) || (ptv == tv_r && pti < ti_r);
      if (pLessT == sameDir) { tv_r = ptv; ti_r = pti; }
    }
  }
  sL[tid] = sv_r; tvL[tid] = tv_r; tiL[tid] = ti_r;

  // inclusive scans of exp(s), exp(0.01 s) in sorted order: wave scan + fixup
  float c1 = __expf(sv_r) , c001 = __expf(0.01f * sv_r);
  {
    float a1 = c1, a2 = c001;
#pragma unroll
    for (int off = 1; off < 64; off <<= 1) {
      const float x1 = __shfl_up(a1, off);
      const float x2 = __shfl_up(a2, off);
      if (lane >= off) { a1 += x1; a2 += x2; }
    }
    if (lane == 63) { ws1[wv_] = a1; ws2[wv_] = a2; }
    __syncthreads();
    float o1 = 0.f, o2 = 0.f;
    for (int ww = 0; ww < 16; ++ww) {
      if (ww < wv_) { o1 += ws1[ww]; o2 += ws2[ww]; }
    }
    c1 = a1 + o1; c001 = a2 + o2;
  }
  cum1L[tid] = c1; cum001L[tid] = c001;
  __syncthreads();
  const float totalHi = cum1L[1023];

  // per sorted-t rank: Z, u = e^t/Z, v = e^{0.01t}/Z
  {
    const float tj = tv_r;
    const float th = -tj;
    int lo = 0, hi = 1024;   // count of sorted-s <= th
    while (lo < hi) { const int mid = (lo + hi) >> 1; if (sL[mid] <= th) lo = mid + 1; else hi = mid; }
    const float S_lo = (lo > 0) ? cum001L[lo - 1] : 0.f;
    const float S_hi = totalHi - ((lo > 0) ? cum1L[lo - 1] : 0.f);
    const float et = __expf(tj), et001 = __expf(0.01f * tj);
    const float Z = et * S_hi + et001 * S_lo;
    const float u = et / Z, v = et001 / Z;
    uL[tid] = u; vL[tid] = v;
    uArr[bh * N_ + tid] = u; vArr[bh * N_ + tid] = v;
    tsi[bh * N_ + tid] = ti_r;
  }

  // query rank for row i=tid: count of t_j <= -s_i (value-only, ties ok)
  {
    const float th = -orig_s;
    int lo = 0, hi = 1024;
    while (lo < hi) { const int mid = (lo + hi) >> 1; if (tvL[mid] <= th) lo = mid + 1; else hi = mid; }
    qrk[bh * N_ + tid] = lo;
  }
  __syncthreads();

  // chunk sums (CH_ chunks of CL_ ranks) of u*Wh, v*Wh + exclusive offsets
  const int c = tid >> 6, d = tid & 63;
#pragma unroll
  for (int half = 0; half < 2; ++half) {
    const int cc = c + half * 16;
    float s1 = 0.f, s2 = 0.f;
    for (int k2 = 0; k2 < CL_; ++k2) {
      const int k = cc * CL_ + k2;
      const int j = tiL[k];
      const float w = Wh[(bh * N_ + j) * D_ + d];
      s1 += uL[k] * w;
      s2 += vL[k] * w;
    }
    cs1[cc * 64 + d] = s1; cs2[cc * 64 + d] = s2;
  }
  __syncthreads();
#pragma unroll
  for (int half = 0; half < 2; ++half) {
    const int cc = c + half * 16;
    float o1 = 0.f, o2 = 0.f;
    for (int m = 0; m < cc; ++m) { o1 += cs1[m * 64 + d]; o2 += cs2[m * 64 + d]; }
    cOff1[(bh * CH_ + cc) * 64 + d] = o1;
    cOff2[(bh * CH_ + cc) * 64 + d] = o2;
  }
}

// ---- Kernel C: inclusive per-rank prefix vectors INC1/INC2 (chunk len 32) --
__global__ __launch_bounds__(64) void k_inc(
    const float* __restrict__ Wh, const int* __restrict__ tsi,
    const float* __restrict__ uArr, const float* __restrict__ vArr,
    const float* __restrict__ cOff1, const float* __restrict__ cOff2,
    float* __restrict__ INC1, float* __restrict__ INC2) {
  const int blk = blockIdx.x;            // bh*CH_ + chunk
  const int bh = blk >> 5, c = blk & (CH_ - 1);
  const int d = threadIdx.x;
  float r1 = cOff1[blk * 64 + d];
  float r2 = cOff2[blk * 64 + d];
  const int base = bh * N_;
#pragma unroll 8
  for (int k2 = 0; k2 < CL_; ++k2) {
    const int k = c * CL_ + k2;
    const int j = tsi[base + k];
    const float u = uArr[base + k], v = vArr[base + k];
    const float w = Wh[(base + j) * D_ + d];
    r1 += u * w;
    r2 += v * w;
    INC1[(base + k) * D_ + d] = r1;
    INC2[(base + k) * D_ + d] = r2;
  }
}

// ---- Kernel C2: hp in registers (wave p == head p), GEMM via readlane ----
__global__ __launch_bounds__(512) void k_out(
    const float* __restrict__ sArr, const int* __restrict__ qrk,
    const float* __restrict__ INC1, const float* __restrict__ INC2,
    const float* __restrict__ outW, const float* __restrict__ outb,
    float* __restrict__ out) {
  __shared__ float part[8 * 8 * 64];
  __shared__ int   rkI[16 * 8];
  __shared__ float esL[16 * 8], es001L[16 * 8];
  const int tid = threadIdx.x;
  const int row0 = blockIdx.x * 16;
  const int b = row0 >> 10;
  const int p = tid >> 6;        // wave id == head hh == k-slice owner
  const int lane = tid & 63;     // d in phase 1, output col in phase 2/3

  if (tid < 128) {
    const int r = tid >> 3, hh = tid & 7;
    const int bh = b * H_ + hh;
    const int n = (row0 + r) & (N_ - 1);
    const float si = sArr[bh * N_ + n];
    rkI[tid] = qrk[bh * N_ + n];
    esL[tid] = __expf(si);
    es001L[tid] = __expf(0.01f * si);
  }
  __syncthreads();

  // phase 1: hpv[r] = hp[row0+r][p*64+lane] entirely in registers
  float hpv[16];
  {
    const int bh = b * H_ + p;
    const float T1 = INC1[(bh * N_ + (N_ - 1)) * D_ + lane];
#pragma unroll
    for (int r = 0; r < 16; ++r) {
      const int rk = rkI[r * 8 + p];
      float i1 = 0.f, i2 = 0.f;
      if (rk > 0) {
        i1 = INC1[(bh * N_ + rk - 1) * D_ + lane];
        i2 = INC2[(bh * N_ + rk - 1) * D_ + lane];
      }
      hpv[r] = esL[r * 8 + p] * (T1 - i1) + es001L[r * 8 + p] * i2;
    }
  }

  // phase 2: wave p owns k in [p*64, p*64+64); hp broadcast via readlane
  float acc[16];
#pragma unroll
  for (int r = 0; r < 16; ++r) acc[r] = 0.f;
#pragma unroll 4
  for (int kc = 0; kc < 64; ++kc) {
    const float wvv = outW[(p * 64 + kc) * 64 + lane];
#pragma unroll
    for (int r = 0; r < 16; ++r) {
      const float hv = bcast_lane(hpv[r], kc);   // SGPR broadcast, no LDS
      acc[r] += hv * wvv;
    }
  }

  // phase 3: reduce the 8 per-wave partials (same order as R2)
  for (int half = 0; half < 2; ++half) {
#pragma unroll
    for (int r = 0; r < 8; ++r) part[(p * 8 + r) * 64 + lane] = acc[half * 8 + r];
    __syncthreads();
    {
      const int r2 = tid >> 6, c2 = tid & 63;
      float ssum = 0.f;
#pragma unroll
      for (int p2 = 0; p2 < 8; ++p2) ssum += part[(p2 * 8 + r2) * 64 + c2];
      out[(row0 + half * 8 + r2) * 64 + c2] = outb[c2] + ssum;
    }
    __syncthreads();
  }
}

extern "C" void kernel_launch(void* const* d_in, const int* in_sizes, int n_in,
                              void* d_out, int out_size, void* d_ws, size_t ws_size,
                              hipStream_t stream) {
  const float* h    = (const float*)d_in[0];
  // d_in[1] = adj: all-ones, unused by the module
  const float* W    = (const float*)d_in[2];
  const float* a    = (const float*)d_in[3];
  const float* outW = (const float*)d_in[4];
  const float* outb = (const float*)d_in[5];
  float* out = (float*)d_out;

  float* ws   = (float*)d_ws;
  float* Wh   = ws;                                   // BH*N*D
  float* sArr = Wh + (size_t)BH_ * N_ * D_;           // BH*N
  float* tArr = sArr + BH_ * N_;
  int*   tsi  = (int*)(tArr + BH_ * N_);
  float* uArr = (float*)(tsi + BH_ * N_);
  float* vArr = uArr + BH_ * N_;
  int*   qrk  = (int*)(vArr + BH_ * N_);
  float* cOff1 = (float*)(qrk + BH_ * N_);            // BH*CH_*64
  float* cOff2 = cOff1 + BH_ * CH_ * 64;
  float* INC1 = cOff2 + BH_ * CH_ * 64;               // BH*N*D
  float* INC2 = INC1 + (size_t)BH_ * N_ * D_;

  hipLaunchKernelGGL(k_wh,   dim3((B_ * N_) / 16), dim3(256), 0, stream,
                     h, W, a, Wh, sArr, tArr);
  hipLaunchKernelGGL(k_sort, dim3(BH_), dim3(1024), 0, stream,
                     sArr, tArr, Wh, tsi, uArr, vArr, qrk, cOff1, cOff2);
  hipLaunchKernelGGL(k_inc,  dim3(BH_ * CH_), dim3(64), 0, stream,
                     Wh, tsi, uArr, vArr, cOff1, cOff2, INC1, INC2);
  hipLaunchKernelGGL(k_out,  dim3((B_ * N_) / 16), dim3(512), 0, stream,
                     sArr, qrk, INC1, INC2, outW, outb, out);
}